// Round 9
// baseline (130.161 us; speedup 1.0000x reference)
//
#include <hip/hip_runtime.h>

typedef unsigned int uint;
typedef unsigned long long u64;
typedef _Float16 f16;
typedef __attribute__((ext_vector_type(8)))  _Float16 f16x8;
typedef __attribute__((ext_vector_type(16))) float    f32x16;
typedef __attribute__((ext_vector_type(4)))  uint     uint4e;

#define NN    10000
#define FD    128
#define HD    32
#define AD    16
#define NPAD  10112      /* 79 * 128 */
#define KPAD  10240      /* 40 * 256 */
#define WORDS 160
#define SEGS  8
#define WPSEG 20         /* mask words per K-segment */
#define NCHUNK 400000    /* NN rows x 40 chunks */

/* ---- K2: FLAT grid-stride pure stream -> mask bits only ------------------
   Chunk c = (row = c/40, k = c%40) covers dwords [k*256, k*256+256) of row.
   Lane l loads dwords k*256 + l*4 .. +3; ballot of element e gives word
   w = k*4+e, bit l <-> col k*256 + l*4 + e (packing as rounds 4-8;
   kp(col) = (col & ~255) | ((col&3)<<6) | ((col&255)>>2) consumed by k3/k4).
   k=39 partial: lanes 0..3 only (cols 9984..9999), high bits zero.
   NO LDS, NO barriers, NO atomics, NO waitcnt asm — deg is recovered by
   popcounting the mask in k3, keeping this loop's VMEM queue pure.        */
__global__ __launch_bounds__(256) void k2_mask(
    const uint* __restrict__ A, u64* __restrict__ mask)
{
  int gw   = (int)(((blockIdx.x << 8) + threadIdx.x) >> 6);  /* global wave */
  int lane = (int)(threadIdx.x & 63);
  const int NW = 2048 * 4;                                   /* 8192 waves */
  #pragma unroll 2
  for (int c = gw; c < NCHUNK; c += NW) {
    int row = c / 40;                  /* magic-mul, c < 2^24 */
    int k   = c - row * 40;
    const uint* base = A + (size_t)row * NN + k * 256 + lane * 4;
    uint4e v = {0u, 0u, 0u, 0u};
    if ((k < 39) | (lane < 4)) v = *(const uint4e*)base;
    u64 b0 = __ballot(v.x != 0u);
    u64 b1 = __ballot(v.y != 0u);
    u64 b2 = __ballot(v.z != 0u);
    u64 b3 = __ballot(v.w != 0u);
    if (lane == 0) {
      u64* mrow = mask + (size_t)row * WORDS + k * 4;
      ulonglong2 s0; s0.x = b0; s0.y = b1;
      ulonglong2 s1; s1.x = b2; s1.y = b3;
      *(ulonglong2*)(mrow)     = s0;
      *(ulonglong2*)(mrow + 2) = s1;
    }
  }
}

/* ---------------- K1: encoder  h = relu(relu(X@W1+b1)@W2+b2), xw = h@Wg ---- */
__global__ __launch_bounds__(256) void k1_encoder(
    const float* __restrict__ X,
    const float* __restrict__ w1g, const float* __restrict__ b1g,
    const float* __restrict__ w2g, const float* __restrict__ b2g,
    const float* __restrict__ wgg,
    float* __restrict__ h_out, float* __restrict__ xw_out)
{
  __shared__ float W1[FD*HD];
  __shared__ float W2[HD*HD];
  __shared__ float WG[HD*HD];
  __shared__ float B1[HD], B2[HD];
  __shared__ float T1[64][36];
  __shared__ float T2[64][36];
  int tid = threadIdx.x;
  for (int v = tid; v < FD*HD/4; v += 256) ((float4*)W1)[v] = ((const float4*)w1g)[v];
  if (tid < HD*HD/4) { ((float4*)W2)[tid] = ((const float4*)w2g)[tid];
                       ((float4*)WG)[tid] = ((const float4*)wgg)[tid]; }
  if (tid < HD) { B1[tid] = b1g[tid]; B2[tid] = b2g[tid]; }
  __syncthreads();

  int r = tid >> 2, cq = tid & 3, c0 = cq * 8;
  int row = blockIdx.x * 64 + r;
  bool valid = row < NN;
  int rs = valid ? row : (NN - 1);

  float acc[8];
  #pragma unroll
  for (int c = 0; c < 8; c++) acc[c] = B1[c0 + c];
  const float4* xp = (const float4*)(X + (size_t)rs * FD);
  for (int k4 = 0; k4 < FD/4; k4++) {
    float4 xv = xp[k4];
    #pragma unroll
    for (int kk = 0; kk < 4; kk++) {
      float x = (&xv.x)[kk];
      const float* wr = &W1[(k4*4 + kk)*HD + c0];
      #pragma unroll
      for (int c = 0; c < 8; c++) acc[c] = fmaf(x, wr[c], acc[c]);
    }
  }
  #pragma unroll
  for (int c = 0; c < 8; c++) T1[r][c0 + c] = fmaxf(acc[c], 0.0f);
  __syncthreads();

  float a2[8];
  #pragma unroll
  for (int c = 0; c < 8; c++) a2[c] = B2[c0 + c];
  for (int k = 0; k < HD; k++) {
    float x = T1[r][k];
    const float* wr = &W2[k*HD + c0];
    #pragma unroll
    for (int c = 0; c < 8; c++) a2[c] = fmaf(x, wr[c], a2[c]);
  }
  #pragma unroll
  for (int c = 0; c < 8; c++) { a2[c] = fmaxf(a2[c], 0.0f); T2[r][c0+c] = a2[c]; }
  if (valid) {
    float4 s0 = {a2[0],a2[1],a2[2],a2[3]}, s1 = {a2[4],a2[5],a2[6],a2[7]};
    ((float4*)(h_out + (size_t)row*HD + c0))[0] = s0;
    ((float4*)(h_out + (size_t)row*HD + c0))[1] = s1;
  }
  __syncthreads();

  float a3[8] = {0,0,0,0,0,0,0,0};
  for (int k = 0; k < HD; k++) {
    float x = T2[r][k];
    const float* wr = &WG[k*HD + c0];
    #pragma unroll
    for (int c = 0; c < 8; c++) a3[c] = fmaf(x, wr[c], a3[c]);
  }
  if (valid) {
    float4 s0 = {a3[0],a3[1],a3[2],a3[3]}, s1 = {a3[4],a3[5],a3[6],a3[7]};
    ((float4*)(xw_out + (size_t)row*HD + c0))[0] = s0;
    ((float4*)(xw_out + (size_t)row*HD + c0))[1] = s1;
  }
}

/* ---- K3: deg = popcount(mask row)+1; dinv = rsqrt; Ytb fragment build ----
   4 threads/row (cq=0..3), each popcounts its 40 mask words; 2x shfl_xor
   reduces within the aligned 4-lane group (validity uniform per group).   */
__global__ __launch_bounds__(256) void k3_scale(
    const u64* __restrict__ mask, const float* __restrict__ xw,
    float* __restrict__ dinv, f16* __restrict__ Ytb)
{
  int tid = threadIdx.x;
  int r = tid >> 2, cq = tid & 3, c0 = cq * 8;
  int row = blockIdx.x * 64 + r;                 /* grid 160 -> rows 0..10239 */
  float y[8];
  float di = 0.0f;
  if (row < NN) {
    const u64* mp = mask + (size_t)row * WORDS + cq * 40;
    uint cnt = 0;
    #pragma unroll 8
    for (int i = 0; i < 40; i++) cnt += (uint)__popcll(mp[i]);
    cnt += (uint)__shfl_xor((int)cnt, 1);
    cnt += (uint)__shfl_xor((int)cnt, 2);
    di = rsqrtf((float)(cnt + 1u));              /* +I self loop */
    if (cq == 0) dinv[row] = di;
    const float4* xp = (const float4*)(xw + (size_t)row * HD + c0);
    float4 u0 = xp[0], u1 = xp[1];
    y[0]=di*u0.x; y[1]=di*u0.y; y[2]=di*u0.z; y[3]=di*u0.w;
    y[4]=di*u1.x; y[5]=di*u1.y; y[6]=di*u1.z; y[7]=di*u1.w;
  } else {
    #pragma unroll
    for (int c = 0; c < 8; c++) y[c] = 0.0f;
  }
  int kp = (row & ~255) | ((row & 3) << 6) | ((row & 255) >> 2);
  f16* yb = Ytb + (size_t)(kp >> 4) * 512 + (kp & 15);
  #pragma unroll
  for (int c = 0; c < 8; c++) yb[(c0 + c) * 16] = (f16)y[c];
}

/* ---------------- K4: SpMM  Cpart[seg] = bits @ Yt  via 32x32x16 f16 MFMA */
__global__ __launch_bounds__(256) void k4_spmm(
    const u64* __restrict__ mask, const f16* __restrict__ Ytb,
    float* __restrict__ Cpart)
{
  __shared__ u64 lm[128][21];                      /* 21: pad for banks */
  __shared__ uint4 lut[256];                       /* byte -> 8 f16 0/1 */
  int tid = threadIdx.x;
  {
    uint b = (uint)tid;
    uint w0 = ((b&1u)  ?0x3C00u:0u) | ((b&2u)  ?0x3C000000u:0u);
    uint w1 = ((b&4u)  ?0x3C00u:0u) | ((b&8u)  ?0x3C000000u:0u);
    uint w2 = ((b&16u) ?0x3C00u:0u) | ((b&32u) ?0x3C000000u:0u);
    uint w3 = ((b&64u) ?0x3C00u:0u) | ((b&128u)?0x3C000000u:0u);
    uint4 e; e.x = w0; e.y = w1; e.z = w2; e.w = w3;
    lut[tid] = e;
  }
  int seg = blockIdx.y;
  int row0 = blockIdx.x * 128;
  for (int idx = tid; idx < 128 * WPSEG; idx += 256) {
    int r = idx / WPSEG, w = idx - r * WPSEG;
    lm[r][w] = mask[(size_t)(row0 + r) * WORDS + seg * WPSEG + w];
  }
  __syncthreads();

  int wave = tid >> 6, lane = tid & 63;
  int col = lane & 31, hi = lane >> 5;
  int rloc = wave * 32 + col;
  const f16* bp = Ytb + (size_t)(seg * 80) * 512 + col * 16 + hi * 8;
  f32x16 acc = {};
  for (int wi = 0; wi < WPSEG; wi++) {
    u64 mw = lm[rloc][wi];
    uint mlo = (uint)mw, mhi = (uint)(mw >> 32);
    #pragma unroll
    for (int q = 0; q < 4; q++) {
      uint hw = (q & 2) ? mhi : mlo;
      uint byte = (hw >> ((q & 1) * 16 + hi * 8)) & 0xFFu;
      union { uint4 u4; f16x8 v; } au;
      au.u4 = lut[byte];
      f16x8 b = *(const f16x8*)(bp + (size_t)(wi * 4 + q) * 512);
      acc = __builtin_amdgcn_mfma_f32_32x32x16_f16(au.v, b, acc, 0, 0, 0);
    }
  }
  int rowbase = row0 + wave * 32;
  float* cp = Cpart + ((size_t)seg * NPAD + rowbase) * HD + col;
  #pragma unroll
  for (int reg = 0; reg < 16; reg++) {
    int rr = (reg & 3) + 8 * (reg >> 2) + 4 * hi;
    int orow = rowbase + rr;
    if (orow < NN) cp[(size_t)rr * HD] = acc[reg];
  }
}

/* ---------------- K5: reduce partials + self-loop + GCN tail + dueling head */
__global__ __launch_bounds__(256) void k5_tail(
    const float* __restrict__ Cpart, const float* __restrict__ dinv,
    const float* __restrict__ xw, const float* __restrict__ h,
    const float* __restrict__ nodemask,
    const float* __restrict__ bg_g, const float* __restrict__ wgd_g, const float* __restrict__ bgd_g,
    const float* __restrict__ wp1_g, const float* __restrict__ bp1_g,
    const float* __restrict__ wp2_g, const float* __restrict__ bp2_g,
    const float* __restrict__ wv_g, const float* __restrict__ bv_g,
    const float* __restrict__ wa_g, const float* __restrict__ ba_g,
    float* __restrict__ out)
{
  __shared__ float WGD[HD*HD], WP2[HD*HD];
  __shared__ float WP1[2*HD*HD];
  __shared__ float WA[HD*AD];
  __shared__ float WV[HD];
  __shared__ float BG[HD], BGD[HD], BP1[HD], BP2[HD], BA[AD];
  __shared__ float BV;
  __shared__ float T1[64][36];
  __shared__ float PIN[64][68];
  __shared__ float RED[64][4];
  int tid = threadIdx.x;

  int r = tid >> 2, cq = tid & 3, c0 = cq * 8;
  int row = blockIdx.x * 64 + r;
  bool valid = row < NN;
  int rs = valid ? row : (NN - 1);
  float di = dinv[rs];
  float mk = nodemask[rs];
  const float4* xp = (const float4*)(xw + (size_t)rs * HD + c0);
  float4 xw0 = xp[0], xw1 = xp[1];
  const float4* hp = (const float4*)(h + (size_t)rs * HD + c0);
  float4 hv0 = hp[0], hv1 = hp[1];
  float4 cpv[16];
  #pragma unroll
  for (int sg = 0; sg < SEGS; sg++) {
    const float4* cp = (const float4*)(Cpart + ((size_t)sg * NPAD + rs) * HD + c0);
    cpv[2*sg]   = cp[0];
    cpv[2*sg+1] = cp[1];
  }

  ((float4*)WGD)[tid] = ((const float4*)wgd_g)[tid];
  for (int v = tid; v < 512; v += 256) ((float4*)WP1)[v] = ((const float4*)wp1_g)[v];
  ((float4*)WP2)[tid] = ((const float4*)wp2_g)[tid];
  if (tid < 128) ((float4*)WA)[tid] = ((const float4*)wa_g)[tid];
  if (tid < HD) { WV[tid] = wv_g[tid]; BG[tid] = bg_g[tid]; BGD[tid] = bgd_g[tid];
                  BP1[tid] = bp1_g[tid]; BP2[tid] = bp2_g[tid]; }
  if (tid < AD) BA[tid] = ba_g[tid];
  if (tid == 0) BV = bv_g[0];
  __syncthreads();

  float s[8];
  s[0]=di*xw0.x; s[1]=di*xw0.y; s[2]=di*xw0.z; s[3]=di*xw0.w;
  s[4]=di*xw1.x; s[5]=di*xw1.y; s[6]=di*xw1.z; s[7]=di*xw1.w;
  #pragma unroll
  for (int sg = 0; sg < SEGS; sg++) {
    float4 u0 = cpv[2*sg], u1 = cpv[2*sg+1];
    s[0]+=u0.x; s[1]+=u0.y; s[2]+=u0.z; s[3]+=u0.w;
    s[4]+=u1.x; s[5]+=u1.y; s[6]+=u1.z; s[7]+=u1.w;
  }
  #pragma unroll
  for (int c = 0; c < 8; c++) T1[r][c0+c] = fmaxf(fmaf(di, s[c], BG[c0+c]), 0.0f);
  __syncthreads();

  float a2[8];
  #pragma unroll
  for (int c = 0; c < 8; c++) a2[c] = BGD[c0+c];
  for (int k = 0; k < HD; k++) {
    float x = T1[r][k];
    const float* wr = &WGD[k*HD + c0];
    #pragma unroll
    for (int c = 0; c < 8; c++) a2[c] = fmaf(x, wr[c], a2[c]);
  }
  #pragma unroll
  for (int c = 0; c < 8; c++) PIN[r][c0+c] = fmaxf(a2[c], 0.0f);
  PIN[r][HD+c0+0]=hv0.x; PIN[r][HD+c0+1]=hv0.y; PIN[r][HD+c0+2]=hv0.z; PIN[r][HD+c0+3]=hv0.w;
  PIN[r][HD+c0+4]=hv1.x; PIN[r][HD+c0+5]=hv1.y; PIN[r][HD+c0+6]=hv1.z; PIN[r][HD+c0+7]=hv1.w;
  __syncthreads();

  float a3[8];
  #pragma unroll
  for (int c = 0; c < 8; c++) a3[c] = BP1[c0+c];
  for (int k = 0; k < 2*HD; k++) {
    float x = PIN[r][k];
    const float* wr = &WP1[k*HD + c0];
    #pragma unroll
    for (int c = 0; c < 8; c++) a3[c] = fmaf(x, wr[c], a3[c]);
  }
  #pragma unroll
  for (int c = 0; c < 8; c++) T1[r][c0+c] = fmaxf(a3[c], 0.0f);
  __syncthreads();

  float a4[8];
  #pragma unroll
  for (int c = 0; c < 8; c++) a4[c] = BP2[c0+c];
  for (int k = 0; k < HD; k++) {
    float x = T1[r][k];
    const float* wr = &WP2[k*HD + c0];
    #pragma unroll
    for (int c = 0; c < 8; c++) a4[c] = fmaf(x, wr[c], a4[c]);
  }
  #pragma unroll
  for (int c = 0; c < 8; c++) PIN[r][c0+c] = fmaxf(a4[c], 0.0f);
  __syncthreads();

  float value = BV;
  for (int k = 0; k < HD; k++) value = fmaf(PIN[r][k], WV[k], value);
  float av[4];
  int j0 = cq * 4;
  #pragma unroll
  for (int j = 0; j < 4; j++) av[j] = BA[j0 + j];
  for (int k = 0; k < HD; k++) {
    float x = PIN[r][k];
    const float* wr = &WA[k*AD + j0];
    #pragma unroll
    for (int j = 0; j < 4; j++) av[j] = fmaf(x, wr[j], av[j]);
  }
  RED[r][cq] = av[0]+av[1]+av[2]+av[3];
  __syncthreads();
  float mean = (RED[r][0]+RED[r][1]+RED[r][2]+RED[r][3]) * (1.0f/AD);
  if (valid) {
    float4 q;
    q.x = (value + av[0] - mean) * mk;
    q.y = (value + av[1] - mean) * mk;
    q.z = (value + av[2] - mean) * mk;
    q.w = (value + av[3] - mean) * mk;
    *((float4*)(out + (size_t)row * AD + j0)) = q;
  }
}

extern "C" void kernel_launch(void* const* d_in, const int* in_sizes, int n_in,
                              void* d_out, int out_size, void* d_ws, size_t ws_size,
                              hipStream_t stream)
{
  const float* X    = (const float*)d_in[0];
  const uint*  A    = (const uint*)d_in[1];
  const float* msk  = (const float*)d_in[2];
  const float* w_e1 = (const float*)d_in[3];
  const float* b_e1 = (const float*)d_in[4];
  const float* w_e2 = (const float*)d_in[5];
  const float* b_e2 = (const float*)d_in[6];
  const float* w_g  = (const float*)d_in[7];
  const float* b_g  = (const float*)d_in[8];
  const float* w_gd = (const float*)d_in[9];
  const float* b_gd = (const float*)d_in[10];
  const float* w_p1 = (const float*)d_in[11];
  const float* b_p1 = (const float*)d_in[12];
  const float* w_p2 = (const float*)d_in[13];
  const float* b_p2 = (const float*)d_in[14];
  const float* w_v  = (const float*)d_in[15];
  const float* b_v  = (const float*)d_in[16];
  const float* w_a  = (const float*)d_in[17];
  const float* b_a  = (const float*)d_in[18];
  float* out = (float*)d_out;

  char* ws = (char*)d_ws;
  /* layout (16B aligned):
     mask   : NPAD*WORDS*8            = 12,943,360 @ 0
     Cpart  : SEGS*NPAD*32*4          = 10,354,688 @ 12,943,360
     Ytb    : 640*512*2 (frag order)  =    655,360 @ 23,298,048
     h      : NN*32*4                 =  1,280,000 @ 23,953,408
     xw     : NN*32*4                 =  1,280,000 @ 25,233,408
     dinv   : NPAD*4                  =     40,448 @ 26,513,408  (~26.6 MB) */
  u64*   maskbits = (u64*)(ws);
  float* Cpart    = (float*)(ws + 12943360);
  f16*   Ytb      = (f16*)(ws + 23298048);
  float* hbuf     = (float*)(ws + 23953408);
  float* xwbuf    = (float*)(ws + 25233408);
  float* dinv     = (float*)(ws + 26513408);

  k2_mask   <<<dim3(2048),           dim3(256), 0, stream>>>(A, maskbits);
  k1_encoder<<<dim3(157),            dim3(256), 0, stream>>>(X, w_e1, b_e1, w_e2, b_e2, w_g, hbuf, xwbuf);
  k3_scale  <<<dim3(160),            dim3(256), 0, stream>>>(maskbits, xwbuf, dinv, Ytb);
  k4_spmm   <<<dim3(NPAD/128, SEGS), dim3(256), 0, stream>>>(maskbits, Ytb, Cpart);
  k5_tail   <<<dim3(157),            dim3(256), 0, stream>>>(Cpart, dinv, xwbuf, hbuf, msk,
                b_g, w_gd, b_gd, w_p1, b_p1, w_p2, b_p2, w_v, b_v, w_a, b_a, out);
}

// Round 10
// 120.168 us; speedup vs baseline: 1.0832x; 1.0832x over previous
//
#include <hip/hip_runtime.h>

typedef unsigned int uint;
typedef unsigned long long u64;
typedef _Float16 f16;
typedef __attribute__((ext_vector_type(8)))  _Float16 f16x8;
typedef __attribute__((ext_vector_type(16))) float    f32x16;
typedef __attribute__((ext_vector_type(4)))  uint     uint4e;

#define NN    10000
#define FD    128
#define HD    32
#define AD    16
#define NPAD  10112      /* 79 * 128 */
#define KPAD  10240      /* 40 * 256 */
#define WORDS 160
#define SEGS  8
#define WPSEG 20         /* mask words per K-segment */

__device__ __forceinline__ void stage1k(const uint* g, uint* l) {
  /* one global_load_lds_dwordx4 per wave: 16B/lane, LDS dest = base + lane*16 */
  __builtin_amdgcn_global_load_lds(
      (const __attribute__((address_space(1))) void*)(g),
      (__attribute__((address_space(3))) void*)(l), 16, 0, 0);
}

/* ---- K2: block-per-row; per-wave 4-deep LDS ring fed by DMA --------------
   Chunk c covers dwords [c*256, c*256+256): lane l holds dwords c*256+l*4..+3.
   Ballot of element e -> mask word w = c*4+e, bit l <-> col c*256+l*4+e.
   Mask words buffered in LDS; one coalesced bulk store at end of row.
   CHAMPION structure (R6, 120.6 us): read-path bound at ~4.2 TB/s.         */
__global__ __launch_bounds__(256) void k2_mask(
    const uint* __restrict__ A, u64* __restrict__ mask, float* __restrict__ degf)
{
  __shared__ __align__(16) uint ring[4][4][256];   /* [wave][slot][dword] 16 KB */
  __shared__ u64 lmask[WORDS];
  __shared__ uint scnt[4];
  int tid = threadIdx.x;
  int wave = tid >> 6, lane = tid & 63;
  int row = blockIdx.x;
  const uint* arow = A + (size_t)row * NN;
  u64* mrow = mask + (size_t)row * WORDS;
  uint* myring = &ring[wave][0][0];

  int niter = (42 - wave) >> 2;                    /* 10,10,10,9 chunks/wave */
  #pragma unroll
  for (int s = 0; s < 4; s++)                      /* prologue: 4 in flight */
    stage1k(arow + (wave + s * 4) * 256 + lane * 4, myring + s * 256);

  uint cnt = 0;
  int t = 0;
  for (; t < niter - 4; t++) {                     /* steady state: counted wait */
    int c = wave + t * 4;
    asm volatile("s_waitcnt vmcnt(3)" ::: "memory");
    uint4e v = *(const uint4e*)(myring + (t & 3) * 256 + lane * 4);
    asm volatile("s_waitcnt lgkmcnt(0)" ::: "memory");  /* v landed before slot reuse */
    stage1k(arow + (c + 16) * 256 + lane * 4, myring + (t & 3) * 256);
    u64 b0 = __ballot(v.x != 0u);
    u64 b1 = __ballot(v.y != 0u);
    u64 b2 = __ballot(v.z != 0u);
    u64 b3 = __ballot(v.w != 0u);
    cnt += (uint)(__popcll(b0) + __popcll(b1) + __popcll(b2) + __popcll(b3));
    if (lane == 0) {
      lmask[c*4+0] = b0; lmask[c*4+1] = b1;
      lmask[c*4+2] = b2; lmask[c*4+3] = b3;
    }
  }
  asm volatile("s_waitcnt vmcnt(0)" ::: "memory"); /* drain last 4 chunks */
  #pragma unroll
  for (int e4 = 0; e4 < 4; e4++, t++) {
    int c = wave + t * 4;
    uint4e v = *(const uint4e*)(myring + (t & 3) * 256 + lane * 4);
    u64 b0 = __ballot(v.x != 0u);
    u64 b1 = __ballot(v.y != 0u);
    u64 b2 = __ballot(v.z != 0u);
    u64 b3 = __ballot(v.w != 0u);
    cnt += (uint)(__popcll(b0) + __popcll(b1) + __popcll(b2) + __popcll(b3));
    if (lane == 0) {
      lmask[c*4+0] = b0; lmask[c*4+1] = b1;
      lmask[c*4+2] = b2; lmask[c*4+3] = b3;
    }
  }
  if (wave == 3) {                                 /* tail: dwords 9984..9999 */
    uint4e v = {0u,0u,0u,0u};
    if (lane < 4) v = *(const uint4e*)(arow + 9984 + lane * 4);
    u64 b0 = __ballot(v.x != 0u);
    u64 b1 = __ballot(v.y != 0u);
    u64 b2 = __ballot(v.z != 0u);
    u64 b3 = __ballot(v.w != 0u);
    cnt += (uint)(__popcll(b0) + __popcll(b1) + __popcll(b2) + __popcll(b3));
    if (lane == 0) {
      lmask[156] = b0; lmask[157] = b1; lmask[158] = b2; lmask[159] = b3;
    }
  }
  if (lane == 0) scnt[wave] = cnt;
  __syncthreads();
  if (tid < WORDS) mrow[tid] = lmask[tid];         /* bulk coalesced store */
  if (tid == 0) degf[row] = (float)(scnt[0] + scnt[1] + scnt[2] + scnt[3] + 1);
}

/* ---- K1: encoder + dinv + fragment-ordered Ytb (runs AFTER k2) ----------
   h = relu(relu(X@W1+b1)@W2+b2); xw = h@Wg; di = rsqrt(deg);
   Ytb[(kp>>4)*512 + c*16 + (kp&15)] = f16(di * xw[c]),
   kp(row) = (row & ~255) | ((row&3)<<6) | ((row&255)>>2).                 */
__global__ __launch_bounds__(256) void k1_encoder(
    const float* __restrict__ X, const float* __restrict__ degf,
    const float* __restrict__ w1g, const float* __restrict__ b1g,
    const float* __restrict__ w2g, const float* __restrict__ b2g,
    const float* __restrict__ wgg,
    float* __restrict__ h_out, float* __restrict__ xw_out,
    float* __restrict__ dinv, f16* __restrict__ Ytb)
{
  __shared__ float W1[FD*HD];
  __shared__ float W2[HD*HD];
  __shared__ float WG[HD*HD];
  __shared__ float B1[HD], B2[HD];
  __shared__ float T1[64][36];
  __shared__ float T2[64][36];
  int tid = threadIdx.x;
  for (int v = tid; v < FD*HD/4; v += 256) ((float4*)W1)[v] = ((const float4*)w1g)[v];
  if (tid < HD*HD/4) { ((float4*)W2)[tid] = ((const float4*)w2g)[tid];
                       ((float4*)WG)[tid] = ((const float4*)wgg)[tid]; }
  if (tid < HD) { B1[tid] = b1g[tid]; B2[tid] = b2g[tid]; }
  __syncthreads();

  int r = tid >> 2, cq = tid & 3, c0 = cq * 8;
  int row = blockIdx.x * 64 + r;
  bool valid = row < NN;
  int rs = valid ? row : (NN - 1);

  float acc[8];
  #pragma unroll
  for (int c = 0; c < 8; c++) acc[c] = B1[c0 + c];
  const float4* xp = (const float4*)(X + (size_t)rs * FD);
  for (int k4 = 0; k4 < FD/4; k4++) {
    float4 xv = xp[k4];
    #pragma unroll
    for (int kk = 0; kk < 4; kk++) {
      float x = (&xv.x)[kk];
      const float* wr = &W1[(k4*4 + kk)*HD + c0];
      #pragma unroll
      for (int c = 0; c < 8; c++) acc[c] = fmaf(x, wr[c], acc[c]);
    }
  }
  #pragma unroll
  for (int c = 0; c < 8; c++) T1[r][c0 + c] = fmaxf(acc[c], 0.0f);
  __syncthreads();

  float a2[8];
  #pragma unroll
  for (int c = 0; c < 8; c++) a2[c] = B2[c0 + c];
  for (int k = 0; k < HD; k++) {
    float x = T1[r][k];
    const float* wr = &W2[k*HD + c0];
    #pragma unroll
    for (int c = 0; c < 8; c++) a2[c] = fmaf(x, wr[c], a2[c]);
  }
  #pragma unroll
  for (int c = 0; c < 8; c++) { a2[c] = fmaxf(a2[c], 0.0f); T2[r][c0+c] = a2[c]; }
  if (valid) {
    float4 s0 = {a2[0],a2[1],a2[2],a2[3]}, s1 = {a2[4],a2[5],a2[6],a2[7]};
    ((float4*)(h_out + (size_t)row*HD + c0))[0] = s0;
    ((float4*)(h_out + (size_t)row*HD + c0))[1] = s1;
  }
  __syncthreads();

  float a3[8] = {0,0,0,0,0,0,0,0};
  for (int k = 0; k < HD; k++) {
    float x = T2[r][k];
    const float* wr = &WG[k*HD + c0];
    #pragma unroll
    for (int c = 0; c < 8; c++) a3[c] = fmaf(x, wr[c], a3[c]);
  }
  if (valid) {
    float4 s0 = {a3[0],a3[1],a3[2],a3[3]}, s1 = {a3[4],a3[5],a3[6],a3[7]};
    ((float4*)(xw_out + (size_t)row*HD + c0))[0] = s0;
    ((float4*)(xw_out + (size_t)row*HD + c0))[1] = s1;
  }

  /* ---- fused Ytb build ---- */
  float di = valid ? rsqrtf(degf[row]) : 0.0f;
  if (valid && cq == 0) dinv[row] = di;
  int kp = (row & ~255) | ((row & 3) << 6) | ((row & 255) >> 2);
  f16* yb = Ytb + (size_t)(kp >> 4) * 512 + (kp & 15);
  #pragma unroll
  for (int c = 0; c < 8; c++) yb[(c0 + c) * 16] = (f16)(di * a3[c]);
}

/* ---------------- K4: SpMM  Cpart[seg] = bits @ Yt  via 32x32x16 f16 MFMA */
__global__ __launch_bounds__(256) void k4_spmm(
    const u64* __restrict__ mask, const f16* __restrict__ Ytb,
    float* __restrict__ Cpart)
{
  __shared__ u64 lm[128][21];                      /* 21: pad for banks */
  __shared__ uint4 lut[256];                       /* byte -> 8 f16 0/1 */
  int tid = threadIdx.x;
  {
    uint b = (uint)tid;
    uint w0 = ((b&1u)  ?0x3C00u:0u) | ((b&2u)  ?0x3C000000u:0u);
    uint w1 = ((b&4u)  ?0x3C00u:0u) | ((b&8u)  ?0x3C000000u:0u);
    uint w2 = ((b&16u) ?0x3C00u:0u) | ((b&32u) ?0x3C000000u:0u);
    uint w3 = ((b&64u) ?0x3C00u:0u) | ((b&128u)?0x3C000000u:0u);
    uint4 e; e.x = w0; e.y = w1; e.z = w2; e.w = w3;
    lut[tid] = e;
  }
  int seg = blockIdx.y;
  int row0 = blockIdx.x * 128;
  for (int idx = tid; idx < 128 * WPSEG; idx += 256) {
    int r = idx / WPSEG, w = idx - r * WPSEG;
    lm[r][w] = mask[(size_t)(row0 + r) * WORDS + seg * WPSEG + w];
  }
  __syncthreads();

  int wave = tid >> 6, lane = tid & 63;
  int col = lane & 31, hi = lane >> 5;
  int rloc = wave * 32 + col;
  const f16* bp = Ytb + (size_t)(seg * 80) * 512 + col * 16 + hi * 8;
  f32x16 acc = {};
  for (int wi = 0; wi < WPSEG; wi++) {
    u64 mw = lm[rloc][wi];
    uint mlo = (uint)mw, mhi = (uint)(mw >> 32);
    #pragma unroll
    for (int q = 0; q < 4; q++) {
      uint hw = (q & 2) ? mhi : mlo;
      uint byte = (hw >> ((q & 1) * 16 + hi * 8)) & 0xFFu;
      union { uint4 u4; f16x8 v; } au;
      au.u4 = lut[byte];
      f16x8 b = *(const f16x8*)(bp + (size_t)(wi * 4 + q) * 512);
      acc = __builtin_amdgcn_mfma_f32_32x32x16_f16(au.v, b, acc, 0, 0, 0);
    }
  }
  int rowbase = row0 + wave * 32;
  float* cp = Cpart + ((size_t)seg * NPAD + rowbase) * HD + col;
  #pragma unroll
  for (int reg = 0; reg < 16; reg++) {
    int rr = (reg & 3) + 8 * (reg >> 2) + 4 * hi;
    int orow = rowbase + rr;
    if (orow < NN) cp[(size_t)rr * HD] = acc[reg];
  }
}

/* ---------------- K5: reduce partials + self-loop + GCN tail + dueling head */
__global__ __launch_bounds__(256) void k5_tail(
    const float* __restrict__ Cpart, const float* __restrict__ dinv,
    const float* __restrict__ xw, const float* __restrict__ h,
    const float* __restrict__ nodemask,
    const float* __restrict__ bg_g, const float* __restrict__ wgd_g, const float* __restrict__ bgd_g,
    const float* __restrict__ wp1_g, const float* __restrict__ bp1_g,
    const float* __restrict__ wp2_g, const float* __restrict__ bp2_g,
    const float* __restrict__ wv_g, const float* __restrict__ bv_g,
    const float* __restrict__ wa_g, const float* __restrict__ ba_g,
    float* __restrict__ out)
{
  __shared__ float WGD[HD*HD], WP2[HD*HD];
  __shared__ float WP1[2*HD*HD];
  __shared__ float WA[HD*AD];
  __shared__ float WV[HD];
  __shared__ float BG[HD], BGD[HD], BP1[HD], BP2[HD], BA[AD];
  __shared__ float BV;
  __shared__ float T1[64][36];
  __shared__ float PIN[64][68];
  __shared__ float RED[64][4];
  int tid = threadIdx.x;

  int r = tid >> 2, cq = tid & 3, c0 = cq * 8;
  int row = blockIdx.x * 64 + r;
  bool valid = row < NN;
  int rs = valid ? row : (NN - 1);
  float di = dinv[rs];
  float mk = nodemask[rs];
  const float4* xp = (const float4*)(xw + (size_t)rs * HD + c0);
  float4 xw0 = xp[0], xw1 = xp[1];
  const float4* hp = (const float4*)(h + (size_t)rs * HD + c0);
  float4 hv0 = hp[0], hv1 = hp[1];
  float4 cpv[16];
  #pragma unroll
  for (int sg = 0; sg < SEGS; sg++) {
    const float4* cp = (const float4*)(Cpart + ((size_t)sg * NPAD + rs) * HD + c0);
    cpv[2*sg]   = cp[0];
    cpv[2*sg+1] = cp[1];
  }

  ((float4*)WGD)[tid] = ((const float4*)wgd_g)[tid];
  for (int v = tid; v < 512; v += 256) ((float4*)WP1)[v] = ((const float4*)wp1_g)[v];
  ((float4*)WP2)[tid] = ((const float4*)wp2_g)[tid];
  if (tid < 128) ((float4*)WA)[tid] = ((const float4*)wa_g)[tid];
  if (tid < HD) { WV[tid] = wv_g[tid]; BG[tid] = bg_g[tid]; BGD[tid] = bgd_g[tid];
                  BP1[tid] = bp1_g[tid]; BP2[tid] = bp2_g[tid]; }
  if (tid < AD) BA[tid] = ba_g[tid];
  if (tid == 0) BV = bv_g[0];
  __syncthreads();

  float s[8];
  s[0]=di*xw0.x; s[1]=di*xw0.y; s[2]=di*xw0.z; s[3]=di*xw0.w;
  s[4]=di*xw1.x; s[5]=di*xw1.y; s[6]=di*xw1.z; s[7]=di*xw1.w;
  #pragma unroll
  for (int sg = 0; sg < SEGS; sg++) {
    float4 u0 = cpv[2*sg], u1 = cpv[2*sg+1];
    s[0]+=u0.x; s[1]+=u0.y; s[2]+=u0.z; s[3]+=u0.w;
    s[4]+=u1.x; s[5]+=u1.y; s[6]+=u1.z; s[7]+=u1.w;
  }
  #pragma unroll
  for (int c = 0; c < 8; c++) T1[r][c0+c] = fmaxf(fmaf(di, s[c], BG[c0+c]), 0.0f);
  __syncthreads();

  float a2[8];
  #pragma unroll
  for (int c = 0; c < 8; c++) a2[c] = BGD[c0+c];
  for (int k = 0; k < HD; k++) {
    float x = T1[r][k];
    const float* wr = &WGD[k*HD + c0];
    #pragma unroll
    for (int c = 0; c < 8; c++) a2[c] = fmaf(x, wr[c], a2[c]);
  }
  #pragma unroll
  for (int c = 0; c < 8; c++) PIN[r][c0+c] = fmaxf(a2[c], 0.0f);
  PIN[r][HD+c0+0]=hv0.x; PIN[r][HD+c0+1]=hv0.y; PIN[r][HD+c0+2]=hv0.z; PIN[r][HD+c0+3]=hv0.w;
  PIN[r][HD+c0+4]=hv1.x; PIN[r][HD+c0+5]=hv1.y; PIN[r][HD+c0+6]=hv1.z; PIN[r][HD+c0+7]=hv1.w;
  __syncthreads();

  float a3[8];
  #pragma unroll
  for (int c = 0; c < 8; c++) a3[c] = BP1[c0+c];
  for (int k = 0; k < 2*HD; k++) {
    float x = PIN[r][k];
    const float* wr = &WP1[k*HD + c0];
    #pragma unroll
    for (int c = 0; c < 8; c++) a3[c] = fmaf(x, wr[c], a3[c]);
  }
  #pragma unroll
  for (int c = 0; c < 8; c++) T1[r][c0+c] = fmaxf(a3[c], 0.0f);
  __syncthreads();

  float a4[8];
  #pragma unroll
  for (int c = 0; c < 8; c++) a4[c] = BP2[c0+c];
  for (int k = 0; k < HD; k++) {
    float x = T1[r][k];
    const float* wr = &WP2[k*HD + c0];
    #pragma unroll
    for (int c = 0; c < 8; c++) a4[c] = fmaf(x, wr[c], a4[c]);
  }
  #pragma unroll
  for (int c = 0; c < 8; c++) PIN[r][c0+c] = fmaxf(a4[c], 0.0f);
  __syncthreads();

  float value = BV;
  for (int k = 0; k < HD; k++) value = fmaf(PIN[r][k], WV[k], value);
  float av[4];
  int j0 = cq * 4;
  #pragma unroll
  for (int j = 0; j < 4; j++) av[j] = BA[j0 + j];
  for (int k = 0; k < HD; k++) {
    float x = PIN[r][k];
    const float* wr = &WA[k*AD + j0];
    #pragma unroll
    for (int j = 0; j < 4; j++) av[j] = fmaf(x, wr[j], av[j]);
  }
  RED[r][cq] = av[0]+av[1]+av[2]+av[3];
  __syncthreads();
  float mean = (RED[r][0]+RED[r][1]+RED[r][2]+RED[r][3]) * (1.0f/AD);
  if (valid) {
    float4 q;
    q.x = (value + av[0] - mean) * mk;
    q.y = (value + av[1] - mean) * mk;
    q.z = (value + av[2] - mean) * mk;
    q.w = (value + av[3] - mean) * mk;
    *((float4*)(out + (size_t)row * AD + j0)) = q;
  }
}

extern "C" void kernel_launch(void* const* d_in, const int* in_sizes, int n_in,
                              void* d_out, int out_size, void* d_ws, size_t ws_size,
                              hipStream_t stream)
{
  const float* X    = (const float*)d_in[0];
  const uint*  A    = (const uint*)d_in[1];
  const float* msk  = (const float*)d_in[2];
  const float* w_e1 = (const float*)d_in[3];
  const float* b_e1 = (const float*)d_in[4];
  const float* w_e2 = (const float*)d_in[5];
  const float* b_e2 = (const float*)d_in[6];
  const float* w_g  = (const float*)d_in[7];
  const float* b_g  = (const float*)d_in[8];
  const float* w_gd = (const float*)d_in[9];
  const float* b_gd = (const float*)d_in[10];
  const float* w_p1 = (const float*)d_in[11];
  const float* b_p1 = (const float*)d_in[12];
  const float* w_p2 = (const float*)d_in[13];
  const float* b_p2 = (const float*)d_in[14];
  const float* w_v  = (const float*)d_in[15];
  const float* b_v  = (const float*)d_in[16];
  const float* w_a  = (const float*)d_in[17];
  const float* b_a  = (const float*)d_in[18];
  float* out = (float*)d_out;

  char* ws = (char*)d_ws;
  /* layout (16B aligned):
     mask   : NPAD*WORDS*8            = 12,943,360 @ 0
     Cpart  : SEGS*NPAD*32*4          = 10,354,688 @ 12,943,360
     Ytb    : 640*512*2 (frag order)  =    655,360 @ 23,298,048
     h      : NN*32*4                 =  1,280,000 @ 23,953,408
     xw     : NN*32*4                 =  1,280,000 @ 25,233,408
     dinv   : NPAD*4                  =     40,448 @ 26,513,408
     degf   : NPAD*4                  =     40,448 @ 26,553,856  (~26.6 MB) */
  u64*   maskbits = (u64*)(ws);
  float* Cpart    = (float*)(ws + 12943360);
  f16*   Ytb      = (f16*)(ws + 23298048);
  float* hbuf     = (float*)(ws + 23953408);
  float* xwbuf    = (float*)(ws + 25233408);
  float* dinv     = (float*)(ws + 26513408);
  float* degf     = (float*)(ws + 26553856);

  k2_mask   <<<dim3(NN),             dim3(256), 0, stream>>>(A, maskbits, degf);
  k1_encoder<<<dim3(160),            dim3(256), 0, stream>>>(X, degf, w_e1, b_e1, w_e2, b_e2, w_g,
                                                             hbuf, xwbuf, dinv, Ytb);
  k4_spmm   <<<dim3(NPAD/128, SEGS), dim3(256), 0, stream>>>(maskbits, Ytb, Cpart);
  k5_tail   <<<dim3(157),            dim3(256), 0, stream>>>(Cpart, dinv, xwbuf, hbuf, msk,
                b_g, w_gd, b_gd, w_p1, b_p1, w_p2, b_p2, w_v, b_v, w_a, b_a, out);
}